// Round 5
// baseline (318.256 us; speedup 1.0000x reference)
//
#include <hip/hip_runtime.h>
#include <hip/hip_bf16.h>
#include <math.h>

// Problem constants
#define C_DIM 256
#define BD    128   // B*D
#define HW    784   // H*W = K
#define CN    128
#define KPAD  832   // 26 k-tiles of 32; rows = 1664 B = 13 x 128 B (line-aligned)
#define KTILES 26

typedef short bf16x8 __attribute__((ext_vector_type(8)));
typedef float f32x4 __attribute__((ext_vector_type(4)));

// fp32 -> bf16 RNE
__device__ inline ushort f2b(float f) {
  unsigned u = __float_as_uint(f);
  unsigned r = (u + 0x7FFFu + ((u >> 16) & 1u)) >> 16;
  return (ushort)r;
}

// ---------------------------------------------------------------------------
// K_a: LN stats (mu, rstd per (bd,hw) point) + cc convert. grid 2944, no LDS.
//   blocks 0..2047  : cc fp32 -> bf16 [C][CN][KPAD] + zero K-pad (unchanged).
//   blocks 2048..   : per-point reduction over c=256 -> stats[bd][hw] float2.
// All global streams here are long contiguous runs (cc reads/writes, x reads;
// stats writes are 128-B runs per pass). The scattered-line transpose writes
// that throttled the one-pass prep (2.2 TB/s) move to K_b in long-run form.
// ---------------------------------------------------------------------------
__global__ __launch_bounds__(256) void stats_cc_kernel(
    const float* __restrict__ x, const float* __restrict__ cc,
    float2* __restrict__ stats, ushort* __restrict__ ccb) {
  const int t = threadIdx.x, bid = blockIdx.x;
  const int w = t >> 6, lane = t & 63;
  const int q = lane >> 4, l = lane & 15;

  if (bid < 2048) {
    // ---------------- cc convert path (unchanged) ----------------
    const int c = bid >> 3;
    const int r = (bid & 7) * 16 + w * 4 + q;
    const float4* src = (const float4*)(cc + ((size_t)c * CN + r) * HW);
    ushort* dst = ccb + ((size_t)c * CN + r) * KPAD;
    float4 v[13];
#pragma unroll
    for (int i = 0; i < 13; ++i) {
      if (i < 12 || l < 4) v[i] = src[i * 16 + l];   // f<196 <=> i<12 || l<4
    }
#pragma unroll
    for (int i = 0; i < 13; ++i) {
      if (i < 12 || l < 4) {
        ushort4 o;
        o.x = f2b(v[i].x); o.y = f2b(v[i].y);
        o.z = f2b(v[i].z); o.w = f2b(v[i].w);
        *(ushort4*)(dst + (i * 16 + l) * 4) = o;
      }
    }
    if (l < 12) *(ushort4*)(dst + 784 + l * 4) = make_ushort4(0, 0, 0, 0);
    return;
  }

  // ---------------- stats path: 896 blocks = 128 bd x 7 tiles of 112 hw ----
  const int sb = bid - 2048;
  const int bd = sb / 7, tile = sb % 7;
  const int hwbase = tile * 112;

#define LOADP(V, p)                                                            \
  do {                                                                         \
    int hw_ = hwbase + (p) * 16 + w * 4 + q;                                   \
    const float* rp = x + ((size_t)bd * HW + hw_) * 256 + l * 4;               \
    V[0] = *(const float4*)rp;       V[1] = *(const float4*)(rp + 64);         \
    V[2] = *(const float4*)(rp + 128); V[3] = *(const float4*)(rp + 192);      \
  } while (0)

#define PROCP(V, p)                                                            \
  do {                                                                         \
    int hw_ = hwbase + (p) * 16 + w * 4 + q;                                   \
    float sum = 0.f, sq = 0.f;                                                 \
    _Pragma("unroll") for (int s = 0; s < 4; ++s) {                            \
      sum += V[s].x + V[s].y + V[s].z + V[s].w;                                \
      sq = fmaf(V[s].x, V[s].x, sq); sq = fmaf(V[s].y, V[s].y, sq);            \
      sq = fmaf(V[s].z, V[s].z, sq); sq = fmaf(V[s].w, V[s].w, sq);            \
    }                                                                          \
    for (int off = 1; off <= 8; off <<= 1) {                                   \
      sum += __shfl_xor(sum, off, 64);                                         \
      sq  += __shfl_xor(sq, off, 64);                                          \
    }                                                                          \
    float mu = sum * (1.f / 256.f);                                            \
    float var = fmaf(-mu, mu, sq * (1.f / 256.f));                             \
    if (l == 0)                                                                \
      stats[(size_t)bd * HW + hw_] = make_float2(mu, rsqrtf(var + 1e-5f));     \
  } while (0)

  // depth-2 pipeline over 7 passes (16 points each)
  float4 va[4], vb[4];
  LOADP(va, 0);
  LOADP(vb, 1); PROCP(va, 0);
  LOADP(va, 2); PROCP(vb, 1);
  LOADP(vb, 3); PROCP(va, 2);
  LOADP(va, 4); PROCP(vb, 3);
  LOADP(vb, 5); PROCP(va, 4);
  LOADP(va, 6); PROCP(vb, 5);
  PROCP(va, 6);
#undef LOADP
#undef PROCP
}

// ---------------------------------------------------------------------------
// K_b: apply LN + transpose -> xre [C][BD][KPAD]. grid 512 = 4 ctiles x 128 bd
// (whole grid resident at 2 blocks/CU). Per block: c-tile of 64 x one bd x
// all k. hw-chunks of 256 (+ tail 16 real + 48 pad):
//   reads  : x[bd][hw][ctile] = 256-B pieces (2 full lines, each line touched
//            by exactly one block chip-wide); x likely L3-warm from K_a.
//   LDS    : btile[64 c][256 hwl] bf16, XOR swizzle hwl^((cc&15)<<2)
//            (transpose writes 8-way, reads 4-way -- both minor phases).
//   writes : per c-row 512-B runs, chunk-sequential => 8-line DRAM runs at
//            212-KB row stride (vs 1-line scattered in the one-pass prep).
// ---------------------------------------------------------------------------
__global__ __launch_bounds__(256) void apply_transpose_kernel(
    const float* __restrict__ x, const float* __restrict__ lnw,
    const float* __restrict__ lnb, const float2* __restrict__ stats,
    ushort* __restrict__ xre) {
  __shared__ __align__(16) ushort btile[64 * 256];  // 32 KB
  __shared__ float2 st_l[256];
  const int t = threadIdx.x;
  const int ct = blockIdx.x & 3, bd = blockIdx.x >> 2;
  const int c0 = ct * 64;
  const int tg = t >> 4, tl = t & 15;    // compute mapping: hw-subrow, c-group
  const int row = t >> 2, rl = t & 3;    // store-out mapping: 4 threads/row
  const float4 wv = *(const float4*)(lnw + c0 + tl * 4);
  const float4 bv = *(const float4*)(lnb + c0 + tl * 4);
  const float* xb = x + (size_t)bd * HW * 256 + c0 + tl * 4;
  const float2* sbp = stats + (size_t)bd * HW;
  const int cc0 = tl * 4;
  const int rsw = (row & 15) << 2;       // store-out row swizzle

  for (int ch = 0; ch < 4; ++ch) {
    const int h0 = ch * 256;
    const bool tail = (ch == 3);         // hw 768..783 real, 784..831 pad
    // stage stats for this chunk (barrier below also guards btile reuse)
    if (!tail) st_l[t] = sbp[h0 + t];
    else if (t < 16) st_l[t] = sbp[h0 + t];
    __syncthreads();
    if (tail) {  // zero pad slots hwl 16..63 through the same swizzle map
#pragma unroll
      for (int z = 0; z < 12; ++z) {
        int hh = 16 + rl * 12 + z;
        btile[row * 256 + (hh ^ rsw)] = 0;
      }
    }
    const int ni = tail ? 1 : 16;
    for (int i = 0; i < ni; ++i) {
      int hwl = tg + i * 16;
      float4 v = *(const float4*)(xb + (size_t)(h0 + hwl) * 256);
      float2 s = st_l[hwl];
      float y0 = (v.x - s.x) * s.y * wv.x + bv.x;
      float y1 = (v.y - s.x) * s.y * wv.y + bv.y;
      float y2 = (v.z - s.x) * s.y * wv.z + bv.z;
      float y3 = (v.w - s.x) * s.y * wv.w + bv.w;
      btile[(cc0 + 0) * 256 + (hwl ^ (((cc0 + 0) & 15) << 2))] = f2b(y0);
      btile[(cc0 + 1) * 256 + (hwl ^ (((cc0 + 1) & 15) << 2))] = f2b(y1);
      btile[(cc0 + 2) * 256 + (hwl ^ (((cc0 + 2) & 15) << 2))] = f2b(y2);
      btile[(cc0 + 3) * 256 + (hwl ^ (((cc0 + 3) & 15) << 2))] = f2b(y3);
    }
    __syncthreads();
    // store-out: 64 rows x (512 B | 128 B tail); uint2 per instr, 4 thr/row
    ushort* drow =
        xre + (size_t)(c0 + row) * (BD * KPAD) + (size_t)bd * KPAD + h0;
    if (!tail) {
#pragma unroll
      for (int i2 = 0; i2 < 16; ++i2) {
        int hwl = rl * 64 + i2 * 4;
        *(uint2*)(drow + hwl) =
            *(const uint2*)&btile[row * 256 + (hwl ^ rsw)];
      }
    } else {
#pragma unroll
      for (int i2 = 0; i2 < 4; ++i2) {
        int hwl = rl * 16 + i2 * 4;
        *(uint2*)(drow + hwl) =
            *(const uint2*)&btile[row * 256 + (hwl ^ rsw)];
      }
    }
  }
}

// ---------------------------------------------------------------------------
// K3: fused MFMA GEMM-dist (round-2 body: double-buffer + __syncthreads;
// the counted-vmcnt ring was neutral-to-negative and is reverted).
// grid 512 (2 blocks per c: m-halves), 256 threads, paired blocks share XCD.
// Norms from MFMA diagonals; all diag extraction statically indexed.
// ---------------------------------------------------------------------------
__global__ __launch_bounds__(256, 2) void gemm_fused_kernel(
    const ushort* __restrict__ xre, const ushort* __restrict__ ccb,
    float* __restrict__ out_d, float* __restrict__ out_s,
    float* __restrict__ out_c) {
  __shared__ __align__(16) ushort At[2][2048];  // 64 rows x 32 k (4 KB/buf)
  __shared__ __align__(16) ushort Bt[2][4096];  // 128 rows x 32 k (8 KB/buf)
  __shared__ float an_l[64], bn_l[128];
  const int bid = blockIdx.x;
  const int xcd = bid & 7, i6 = bid >> 3;
  const int c = xcd * 32 + (i6 >> 1);           // paired blocks -> same XCD
  const int h = i6 & 1;                          // m-half
  const int t = threadIdx.x, w = t >> 6, lane = t & 63;
  const int quad = lane >> 4, ln = lane & 15;
  const ushort* Ag = xre + (size_t)c * (128 * KPAD) + (size_t)(h * 64) * KPAD;
  const ushort* Bg = ccb + (size_t)c * (128 * KPAD);

  f32x4 accx[8], accc[8];
  f32x4 accd  = f32x4{0.f, 0.f, 0.f, 0.f};
  f32x4 accbd = f32x4{0.f, 0.f, 0.f, 0.f};
#pragma unroll
  for (int j = 0; j < 8; ++j) {
    accx[j] = f32x4{0.f, 0.f, 0.f, 0.f};
    accc[j] = f32x4{0.f, 0.f, 0.f, 0.f};
  }

  const int srow = t >> 2, scq = (t & 3) ^ (srow & 3);
  const ushort* gA  = Ag + (size_t)srow * KPAD + scq * 8;
  const ushort* gB1 = Bg + (size_t)srow * KPAD + scq * 8;
  const ushort* gB2 = Bg + (size_t)(srow + 64) * KPAD + scq * 8;

  const int m = w * 16 + ln;                         // local m row 0..63
  const int aoff  = (m * 4 + (quad ^ (m & 3))) * 8;              // At row m
  const int aroff = ((h * 64 + m) * 4 + (quad ^ (m & 3))) * 8;   // Bt row m_g
  const int nD = (1 - h) * 64 + w * 16 + ln;         // other-half B-diag row
  const int bdoff = (nD * 4 + (quad ^ (nD & 3))) * 8;
  int boff[8];
#pragma unroll
  for (int j = 0; j < 8; ++j) {
    int n = j * 16 + ln;
    boff[j] = (n * 4 + (quad ^ (n & 3))) * 8;
  }

#define ISSUE(k, p)                                                            \
  do {                                                                         \
    int kb = (k) * 32;                                                         \
    __builtin_amdgcn_global_load_lds(                                          \
        (const __attribute__((address_space(1))) unsigned int*)(gA + kb),      \
        (__attribute__((address_space(3))) unsigned int*)&At[p][t * 8], 16, 0, 0); \
    __builtin_amdgcn_global_load_lds(                                          \
        (const __attribute__((address_space(1))) unsigned int*)(gB1 + kb),     \
        (__attribute__((address_space(3))) unsigned int*)&Bt[p][t * 8], 16, 0, 0); \
    __builtin_amdgcn_global_load_lds(                                          \
        (const __attribute__((address_space(1))) unsigned int*)(gB2 + kb),     \
        (__attribute__((address_space(3))) unsigned int*)&Bt[p][t * 8 + 2048], 16, 0, 0); \
  } while (0)

  ISSUE(0, 0);
  for (int k0 = 0; k0 < KTILES; ++k0) {
    __syncthreads();
    if (k0 < KTILES - 1) ISSUE(k0 + 1, (k0 + 1) & 1);
    const int p = k0 & 1;
    bf16x8 af  = *(const bf16x8*)&At[p][aoff];   // x_re row (local m)
    bf16x8 ar  = *(const bf16x8*)&Bt[p][aroff];  // cc row (global m)
    bf16x8 bdr = *(const bf16x8*)&Bt[p][bdoff];  // cc row (other-half diag)
    accd  = __builtin_amdgcn_mfma_f32_16x16x32_bf16(af, af, accd, 0, 0, 0);
    accbd = __builtin_amdgcn_mfma_f32_16x16x32_bf16(bdr, bdr, accbd, 0, 0, 0);
#pragma unroll
    for (int j = 0; j < 8; ++j) {
      bf16x8 bfj = *(const bf16x8*)&Bt[p][boff[j]];
      accx[j] = __builtin_amdgcn_mfma_f32_16x16x32_bf16(af, bfj, accx[j], 0, 0, 0);
      accc[j] = __builtin_amdgcn_mfma_f32_16x16x32_bf16(ar, bfj, accc[j], 0, 0, 0);
    }
  }
#undef ISSUE

  __syncthreads();
  // publish diagonals (all acc indices compile-time static)
  if ((ln >> 2) == quad) {
#pragma unroll
    for (int r2 = 0; r2 < 4; ++r2)
      if (r2 == (ln & 3)) {
        an_l[w * 16 + ln] = accd[r2];                    // ||a||^2, local m
        bn_l[(1 - h) * 64 + w * 16 + ln] = accbd[r2];    // ||b||^2 other half
      }
#pragma unroll
    for (int j = 0; j < 8; ++j)
      if (j == h * 4 + w) {
#pragma unroll
        for (int r2 = 0; r2 < 4; ++r2)
          if (r2 == (ln & 3))
            bn_l[h * 64 + w * 16 + ln] = accc[j][r2];    // ||b||^2 own half
      }
  }
  __syncthreads();

  float cn[8];
#pragma unroll
  for (int j = 0; j < 8; ++j) cn[j] = bn_l[j * 16 + ln];
  float rx[4], rc[4];
#pragma unroll
  for (int r = 0; r < 4; ++r) {
    rx[r] = an_l[w * 16 + quad * 4 + r];
    rc[r] = bn_l[h * 64 + w * 16 + quad * 4 + r];
  }
  // cluster_dist
#pragma unroll
  for (int r = 0; r < 4; ++r) {
    int mr = h * 64 + w * 16 + quad * 4 + r;
    float* ob = out_c + (size_t)c * (128 * 128) + (size_t)mr * 128;
#pragma unroll
    for (int j = 0; j < 8; ++j) {
      float d2 = rc[r] + cn[j] - 2.f * accc[j][r];
      ob[j * 16 + ln] = sqrtf(fmaxf(d2, 1e-12f));
    }
  }
  // x_distance + softmax (row fully in-quad: 8 regs x 16 ln)
#pragma unroll
  for (int r = 0; r < 4; ++r) {
    int mr = h * 64 + w * 16 + quad * 4 + r;
    float dr[8];
#pragma unroll
    for (int j = 0; j < 8; ++j) {
      float d2 = rx[r] + cn[j] - 2.f * accx[j][r];
      dr[j] = sqrtf(fmaxf(d2, 1e-12f));
    }
    float* ob = out_d + ((size_t)mr * 256 + c) * 128;
#pragma unroll
    for (int j = 0; j < 8; ++j) ob[j * 16 + ln] = dr[j];
    float mn = dr[0];
#pragma unroll
    for (int j = 1; j < 8; ++j) mn = fminf(mn, dr[j]);
    for (int off = 1; off <= 8; off <<= 1) mn = fminf(mn, __shfl_xor(mn, off, 64));
    float e[8], s = 0.f;
#pragma unroll
    for (int j = 0; j < 8; ++j) { e[j] = __expf(-32.f * (dr[j] - mn)); s += e[j]; }
    for (int off = 1; off <= 8; off <<= 1) s += __shfl_xor(s, off, 64);
    float inv = 1.f / s;
    float* os = out_s + ((size_t)mr * 256 + c) * 128;
#pragma unroll
    for (int j = 0; j < 8; ++j) os[j * 16 + ln] = e[j] * inv;
  }
}

extern "C" void kernel_launch(void* const* d_in, const int* in_sizes, int n_in,
                              void* d_out, int out_size, void* d_ws, size_t ws_size,
                              hipStream_t stream) {
  const float* x   = (const float*)d_in[0];
  const float* lnw = (const float*)d_in[1];
  const float* lnb = (const float*)d_in[2];
  const float* cc  = (const float*)d_in[3];
  float* out   = (float*)d_out;
  float* out_d = out;             // x_distance        [8,16,256,128]
  float* out_s = out + 4194304;   // x_distance_assign [8,16,256,128]
  float* out_c = out + 8388608;   // cluster_dist      [256,128,128]

  ushort* xre_b = (ushort*)d_ws;              // 256*128*832 bf16 = 54.5 MB
  ushort* cc_b  = xre_b + 27262976;           // 54.5 MB
  float2* stats = (float2*)(cc_b + 27262976); // 128*784 float2 = 0.8 MB

  // K_a: 2048 cc-convert blocks + 896 stats blocks (no LDS, all-contiguous IO)
  stats_cc_kernel<<<2944, 256, 0, stream>>>(x, cc, stats, cc_b);
  // K_b: apply LN + transpose with long-run writes
  apply_transpose_kernel<<<512, 256, 0, stream>>>(x, lnw, lnb, stats, xre_b);
  gemm_fused_kernel<<<512, 256, 0, stream>>>(xre_b, cc_b, out_d, out_s, out_c);
}